// Round 2
// 3997.670 us; speedup vs baseline: 2.2516x; 2.2516x over previous
//
#include <hip/hip_runtime.h>

// ---------------------------------------------------------------------------
// PolicyNet2 forward. bf16x3 split-MFMA GEMMs (on-the-fly f32->bf16 conversion
// where workspace doesn't allow precomputed planes), fp32 attention/LN/head.
// B=512 S=128 E=640 A=129 H=2048 NHEADS=10 HD=64 K_WIN=64
// Workspace footprint: exactly 694,157,312 bytes (== previously proven max).
// ---------------------------------------------------------------------------

#define BB   512
#define SS   128
#define EE   640
#define AA   129
#define HH   2048
#define NH   10
#define HD   64

// ---------------- workspace layout (bytes) ----------------
#define WS_QKV      0LL            // [65536,1920] f32 qkv; ctx in-place q-slice; AO in k-slice
#define WS_W2HI     0LL            // post-LN640: qkv dead -> w2/w3/w4 planes live here
#define WS_W2LO     8388608LL
#define WS_W3HI     16777216LL
#define WS_W3LO     20971520LL
#define WS_W4HI     25165824LL
#define WS_W4LO     26214400LL
#define WS_HHI      503316480LL    // [65536,640] u16 h hi ; later x hi
#define WS_HLO      587202560LL    // [65536,640] u16 h lo ; later x lo
#define WS_XHI      503316480LL
#define WS_XLO      587202560LL
#define WS_C1       671088640LL    // [512,2048] f32
#define WS_C2       675282944LL    // [512,2048]
#define WS_C3       679477248LL    // [512,1024]
#define WS_C4       681574400LL    // [512,512]
#define WS_X1HI     682622976LL    // [512,2048] u16
#define WS_X1LO     684720128LL
#define WS_X2HI     686817280LL
#define WS_X2LO     688914432LL
#define WS_X3HI     691011584LL    // [512,1024] u16
#define WS_X3LO     692060160LL
#define WS_X4F      693108736LL    // [512,512] f32  (ends at 694,157,312)
#define WS_ZERO_LEN 11534336LL     // C1..C4 contiguous

typedef __bf16 bf16x8 __attribute__((ext_vector_type(8)));
typedef float  f32x4  __attribute__((ext_vector_type(4)));
typedef unsigned short us8 __attribute__((ext_vector_type(8)));

// ---------------- fp32 -> bf16 hi/lo split (RNE both) ----------------
__device__ __forceinline__ unsigned int bf16_rne(float x) {
    unsigned int u = __float_as_uint(x);
    return (u + 0x7fffu + ((u >> 16) & 1u)) >> 16;
}
__device__ __forceinline__ void split2(float x, unsigned short& h, unsigned short& l) {
    const unsigned int hb = bf16_rne(x);
    const float hf = __uint_as_float(hb << 16);
    const unsigned int lb = bf16_rne(x - hf);
    h = (unsigned short)hb; l = (unsigned short)lb;
}
__device__ __forceinline__ float bf2f(unsigned short v) {
    return __uint_as_float((unsigned int)v << 16);
}

// ---------------- async global->LDS, 16B/lane ----------------
__device__ __forceinline__ void gload16(const unsigned short* g, unsigned short* l) {
    __builtin_amdgcn_global_load_lds(
        (__attribute__((address_space(1))) unsigned int*)g,
        (__attribute__((address_space(3))) unsigned int*)l, 16, 0, 0);
}

// stage 8 f32 -> 8 bf16-hi + 8 bf16-lo into LDS (16B each)
__device__ __forceinline__ void stage_otf(const float* src, int align4,
                                          unsigned short* dhi, unsigned short* dlo) {
    float f[8];
    if (align4) {
        const float4 v0 = *reinterpret_cast<const float4*>(src);
        const float4 v1 = *reinterpret_cast<const float4*>(src + 4);
        f[0] = v0.x; f[1] = v0.y; f[2] = v0.z; f[3] = v0.w;
        f[4] = v1.x; f[5] = v1.y; f[6] = v1.z; f[7] = v1.w;
    } else {
#pragma unroll
        for (int j = 0; j < 8; ++j) f[j] = src[j];
    }
    us8 h, l;
#pragma unroll
    for (int j = 0; j < 8; ++j) {
        unsigned short hh, ll; split2(f[j], hh, ll);
        h[j] = hh; l[j] = ll;
    }
    *reinterpret_cast<us8*>(dhi) = h;
    *reinterpret_cast<us8*>(dlo) = l;
}

// ---------------------------------------------------------------------------
// MFMA bf16x3 GEMM: C[m,n] (+)= sum_k A[m,k]*B[n,k]
// Operands either pre-split bf16 planes (global_load_lds path) or f32
// (reg-stage + split on the fly). 128x128 tile, BK=32, 256 thr (4 waves,
// each 64x64 = 4x4 16x16x32 frags).
// LDS 16B-chunk swizzle: chunk(row r, source-slot s) stored at position
// r*4 + (s ^ ((r>>1)&3)); both staging paths write the identical layout.
// Requires: M,N multiples of 128; kChunk multiple of 32.
// ---------------------------------------------------------------------------
struct MGemmP {
    const unsigned short *Ahi, *Alo, *Bhi, *Blo;   // plane path
    const float *Af32, *Bf32;                      // on-the-fly path
    float* C;
    const float* bias; const float* resid;
    const unsigned short *Rhi, *Rlo;               // resid from planes (hi+lo)
    unsigned short *Chi, *Clo;                     // optional plane outputs
    long long lda, ldb, ldc, ldr;                  // element strides
    int kChunk; int act; int aAlign4, bAlign4;
};

template <bool ATOMIC, bool AOTF, bool BOTF>
__global__ __launch_bounds__(256, 2)
void gemm_mfma(MGemmP p) {
    __shared__ __align__(16) unsigned short sAhi[4096];
    __shared__ __align__(16) unsigned short sAlo[4096];
    __shared__ __align__(16) unsigned short sBhi[4096];
    __shared__ __align__(16) unsigned short sBlo[4096];
    const int tid = threadIdx.x;
    const int lane = tid & 63, wave = tid >> 6;
    const int n0 = blockIdx.x * 128, m0 = blockIdx.y * 128;
    const long long kS = (long long)blockIdx.z * p.kChunk;
    const long long kE = kS + p.kChunk;
    const int wr = (wave >> 1) * 64, wc = (wave & 1) * 64;

    // fragment LDS offsets (swizzled), conflict-free ds_read_b128
    int aoff[4], boff[4];
#pragma unroll
    for (int i = 0; i < 4; ++i) {
        const int ks = lane >> 4;
        const int ar = wr + i * 16 + (lane & 15);
        aoff[i] = (ar * 4 + (ks ^ ((ar >> 1) & 3))) * 8;
        const int br = wc + i * 16 + (lane & 15);
        boff[i] = (br * 4 + (ks ^ ((br >> 1) & 3))) * 8;
    }

    // staging coords: 2 rounds x 256 chunks of 16B; source slot inverse-swizzled
    long long gA[2], gB[2];
    int ldsU[2], ldsP[2];
#pragma unroll
    for (int c = 0; c < 2; ++c) {
        const int ch = c * 256 + tid;
        const int r  = ch >> 2;
        const int s  = (ch & 3) ^ ((r >> 1) & 3);
        gA[c] = (long long)(m0 + r) * p.lda + s * 8;
        gB[c] = (long long)(n0 + r) * p.ldb + s * 8;
        ldsU[c] = (c * 256 + wave * 64) * 8;   // wave-uniform base for gload_lds
        ldsP[c] = ch * 8;                      // per-lane for ds_write path
    }

    f32x4 acc[4][4];
    const f32x4 zero = {0.f, 0.f, 0.f, 0.f};
#pragma unroll
    for (int i = 0; i < 4; ++i)
#pragma unroll
        for (int j = 0; j < 4; ++j) acc[i][j] = zero;

    for (long long kt = kS; kt < kE; kt += 32) {
#pragma unroll
        for (int c = 0; c < 2; ++c) {
            if (AOTF) {
                stage_otf(p.Af32 + gA[c] + kt, p.aAlign4, &sAhi[ldsP[c]], &sAlo[ldsP[c]]);
            } else {
                gload16(p.Ahi + gA[c] + kt, &sAhi[ldsU[c]]);
                gload16(p.Alo + gA[c] + kt, &sAlo[ldsU[c]]);
            }
            if (BOTF) {
                stage_otf(p.Bf32 + gB[c] + kt, p.bAlign4, &sBhi[ldsP[c]], &sBlo[ldsP[c]]);
            } else {
                gload16(p.Bhi + gB[c] + kt, &sBhi[ldsU[c]]);
                gload16(p.Blo + gB[c] + kt, &sBlo[ldsU[c]]);
            }
        }
        __syncthreads();
        bf16x8 ah[4], al[4], bh[4], bl[4];
#pragma unroll
        for (int i = 0; i < 4; ++i) {
            ah[i] = *(const bf16x8*)&sAhi[aoff[i]];
            al[i] = *(const bf16x8*)&sAlo[aoff[i]];
            bh[i] = *(const bf16x8*)&sBhi[boff[i]];
            bl[i] = *(const bf16x8*)&sBlo[boff[i]];
        }
#pragma unroll
        for (int mi = 0; mi < 4; ++mi)
#pragma unroll
            for (int ni = 0; ni < 4; ++ni) {
                acc[mi][ni] = __builtin_amdgcn_mfma_f32_16x16x32_bf16(ah[mi], bh[ni], acc[mi][ni], 0, 0, 0);
                acc[mi][ni] = __builtin_amdgcn_mfma_f32_16x16x32_bf16(ah[mi], bl[ni], acc[mi][ni], 0, 0, 0);
                acc[mi][ni] = __builtin_amdgcn_mfma_f32_16x16x32_bf16(al[mi], bh[ni], acc[mi][ni], 0, 0, 0);
            }
        __syncthreads();
    }

    // epilogue: C/D frag layout col=lane&15, row=(lane>>4)*4+reg  [m89/m91]
    const int rb = (lane >> 4) * 4, ci = lane & 15;
#pragma unroll
    for (int mi = 0; mi < 4; ++mi)
#pragma unroll
        for (int r = 0; r < 4; ++r) {
            const long long row = (long long)(m0 + wr + mi * 16 + rb + r);
#pragma unroll
            for (int ni = 0; ni < 4; ++ni) {
                const int col = n0 + wc + ni * 16 + ci;
                float v = acc[mi][ni][r];
                if (ATOMIC) {
                    unsafeAtomicAdd(&p.C[row * p.ldc + col], v);
                } else {
                    if (p.bias)  v += p.bias[col];
                    if (p.resid) v += p.resid[row * p.ldr + col];
                    if (p.Rhi) {
                        const long long ri = row * p.ldr + col;
                        v += bf2f(p.Rhi[ri]) + bf2f(p.Rlo[ri]);
                    }
                    if (p.act)   v = fmaxf(v, 0.f);
                    if (p.C)     p.C[row * p.ldc + col] = v;
                    if (p.Chi) {
                        unsigned short h, l; split2(v, h, l);
                        p.Chi[row * p.ldc + col] = h;
                        p.Clo[row * p.ldc + col] = l;
                    }
                }
            }
        }
}

// ---------------------------------------------------------------------------
// fp32 fallback GEMM (only fc1's 129-wide last_action tail). Proven.
// ---------------------------------------------------------------------------
struct GemmP {
    const float* A; const float* B; float* C;
    const float* bias; const float* resid;
    int lda, ldb, ldc, ldr;
    int kStart, kEnd, kChunk, kOffA;
    int act;
};

template <bool ATOMIC>
__global__ __launch_bounds__(256)
void gemm128(GemmP p) {
    __shared__ float As[16 * 128];
    __shared__ float Bs[16 * 128];
    const int tid = threadIdx.x;
    const int m0 = blockIdx.x * 128;
    const int n0 = blockIdx.y * 128;
    int kS = p.kStart + (int)blockIdx.z * p.kChunk;
    int kE = kS + p.kChunk; if (kE > p.kEnd) kE = p.kEnd;
    const int tx = tid & 15, ty = tid >> 4;

    float acc[8][8];
#pragma unroll
    for (int i = 0; i < 8; ++i)
#pragma unroll
        for (int j = 0; j < 8; ++j) acc[i][j] = 0.f;

    const bool a4 = ((p.lda & 3) == 0);
    const bool b4 = ((p.ldb & 3) == 0);

    for (int kt = kS; kt < kE; kt += 16) {
#pragma unroll
        for (int it = 0; it < 2; ++it) {
            const int slot = tid + it * 256;
            const int row = slot >> 2;
            const int kq  = (slot & 3) << 2;
            const int k   = kt + kq;
            {
                const float* ap = p.A + (long long)(m0 + row) * p.lda + (k - p.kOffA);
                float4 v;
                if (a4 && (k + 4 <= kE)) {
                    v = *reinterpret_cast<const float4*>(ap);
                } else {
                    v.x = (k + 0 < kE) ? ap[0] : 0.f;
                    v.y = (k + 1 < kE) ? ap[1] : 0.f;
                    v.z = (k + 2 < kE) ? ap[2] : 0.f;
                    v.w = (k + 3 < kE) ? ap[3] : 0.f;
                }
                As[(kq + 0) * 128 + row] = v.x;
                As[(kq + 1) * 128 + row] = v.y;
                As[(kq + 2) * 128 + row] = v.z;
                As[(kq + 3) * 128 + row] = v.w;
            }
            {
                const float* bp = p.B + (long long)(n0 + row) * p.ldb + k;
                float4 v;
                if (b4 && (k + 4 <= kE)) {
                    v = *reinterpret_cast<const float4*>(bp);
                } else {
                    v.x = (k + 0 < kE) ? bp[0] : 0.f;
                    v.y = (k + 1 < kE) ? bp[1] : 0.f;
                    v.z = (k + 2 < kE) ? bp[2] : 0.f;
                    v.w = (k + 3 < kE) ? bp[3] : 0.f;
                }
                Bs[(kq + 0) * 128 + row] = v.x;
                Bs[(kq + 1) * 128 + row] = v.y;
                Bs[(kq + 2) * 128 + row] = v.z;
                Bs[(kq + 3) * 128 + row] = v.w;
            }
        }
        __syncthreads();
#pragma unroll
        for (int kk = 0; kk < 16; ++kk) {
            float a[8], b[8];
            *reinterpret_cast<float4*>(&a[0]) = *reinterpret_cast<const float4*>(&As[kk * 128 + ty * 8]);
            *reinterpret_cast<float4*>(&a[4]) = *reinterpret_cast<const float4*>(&As[kk * 128 + ty * 8 + 4]);
            *reinterpret_cast<float4*>(&b[0]) = *reinterpret_cast<const float4*>(&Bs[kk * 128 + tx * 8]);
            *reinterpret_cast<float4*>(&b[4]) = *reinterpret_cast<const float4*>(&Bs[kk * 128 + tx * 8 + 4]);
#pragma unroll
            for (int i = 0; i < 8; ++i)
#pragma unroll
                for (int j = 0; j < 8; ++j) acc[i][j] += a[i] * b[j];
        }
        __syncthreads();
    }

#pragma unroll
    for (int i = 0; i < 8; ++i) {
        const int row = m0 + ty * 8 + i;
        const long long cb = (long long)row * p.ldc + n0 + tx * 8;
        if (ATOMIC) {
#pragma unroll
            for (int j = 0; j < 8; ++j) unsafeAtomicAdd(&p.C[cb + j], acc[i][j]);
        } else {
            const long long rb = (long long)row * p.ldr + n0 + tx * 8;
#pragma unroll
            for (int j = 0; j < 8; ++j) {
                float v = acc[i][j];
                if (p.bias)  v += p.bias[n0 + tx * 8 + j];
                if (p.resid) v += p.resid[rb + j];
                if (p.act)   v = fmaxf(v, 0.f);
                p.C[cb + j] = v;
            }
        }
    }
}

// ---------------------------------------------------------------------------
// split: fp32 -> bf16 hi/lo planes (for w2/w3/w4 only)
// ---------------------------------------------------------------------------
typedef unsigned short us4 __attribute__((ext_vector_type(4)));
__global__ __launch_bounds__(256)
void split_kernel(const float* __restrict__ in, unsigned short* __restrict__ hi,
                  unsigned short* __restrict__ lo, long long n4) {
    const long long stride = (long long)gridDim.x * 256;
    for (long long i = (long long)blockIdx.x * 256 + threadIdx.x; i < n4; i += stride) {
        const float4 v = reinterpret_cast<const float4*>(in)[i];
        unsigned short h0, h1, h2, h3, l0, l1, l2, l3;
        split2(v.x, h0, l0); split2(v.y, h1, l1);
        split2(v.z, h2, l2); split2(v.w, h3, l3);
        us4 hv = {h0, h1, h2, h3};
        us4 lv = {l0, l1, l2, l3};
        reinterpret_cast<us4*>(hi)[i] = hv;
        reinterpret_cast<us4*>(lo)[i] = lv;
    }
}

// out planes = split(relu(c + bias))
__global__ __launch_bounds__(256)
void bias_act_split_kernel(const float* __restrict__ c, const float* __restrict__ bias,
                           unsigned short* __restrict__ hi,
                           unsigned short* __restrict__ lo, int mask) {
    const int idx = blockIdx.x * 256 + threadIdx.x;
    const float v = fmaxf(c[idx] + bias[idx & mask], 0.f);
    unsigned short h, l; split2(v, h, l);
    hi[idx] = h; lo[idx] = l;
}

__global__ __launch_bounds__(256)
void bias_relu_kernel(const float* c, const float* bias, float* out, int mask) {
    const int idx = blockIdx.x * 256 + threadIdx.x;
    out[idx] = fmaxf(c[idx] + bias[idx & mask], 0.f);
}

// ---------------------------------------------------------------------------
// Attention: one workgroup per (b, head). In-place: ctx -> q slice. (proven)
// ---------------------------------------------------------------------------
__global__ __launch_bounds__(256)
void attn_kernel(float* qkv) {
    __shared__ float qs[128 * 65];
    __shared__ float ks[128 * 65];
    __shared__ float sc[128 * 129];
    const int tid = threadIdx.x;
    const int b = blockIdx.x / NH, h = blockIdx.x % NH;
    const long long base = (long long)b * SS * (3 * EE) + h * HD;

    for (int idx = tid; idx < 128 * 64; idx += 256) {
        const int s = idx >> 6, d = idx & 63;
        qs[s * 65 + d] = qkv[base + (long long)s * 1920 + d] * 0.125f;
        ks[s * 65 + d] = qkv[base + 640 + (long long)s * 1920 + d];
    }
    __syncthreads();

    {
        const int tx = tid & 15, ty = tid >> 4;
        const int i0 = ty * 8, j0 = tx * 8;
        float acc[8][8];
#pragma unroll
        for (int i = 0; i < 8; ++i)
#pragma unroll
            for (int j = 0; j < 8; ++j) acc[i][j] = 0.f;
#pragma unroll 4
        for (int d = 0; d < 64; ++d) {
            float qa[8], kb[8];
#pragma unroll
            for (int i = 0; i < 8; ++i) qa[i] = qs[(i0 + i) * 65 + d];
#pragma unroll
            for (int j = 0; j < 8; ++j) kb[j] = ks[(j0 + j) * 65 + d];
#pragma unroll
            for (int i = 0; i < 8; ++i)
#pragma unroll
                for (int j = 0; j < 8; ++j) acc[i][j] += qa[i] * kb[j];
        }
#pragma unroll
        for (int i = 0; i < 8; ++i)
#pragma unroll
            for (int j = 0; j < 8; ++j) sc[(i0 + i) * 129 + (j0 + j)] = acc[i][j];
    }
    __syncthreads();

    if (tid < 128) {
        const int r = tid;
        float m = -3.402823466e38f;
        for (int j = 0; j < 128; ++j) m = fmaxf(m, sc[r * 129 + j]);
        float sum = 0.f;
        for (int j = 0; j < 128; ++j) {
            const float e = expf(sc[r * 129 + j] - m);
            sc[r * 129 + j] = e; sum += e;
        }
        const float inv = 1.f / sum;
        for (int j = 0; j < 128; ++j) sc[r * 129 + j] *= inv;
    }
    __syncthreads();

    for (int idx = tid; idx < 128 * 64; idx += 256) {
        const int s = idx >> 6, d = idx & 63;
        qs[s * 65 + d] = qkv[base + 1280 + (long long)s * 1920 + d];
    }
    __syncthreads();

    {
        const int cx = tid & 7, cy = tid >> 3;
        const int i0 = cy * 4, d0 = cx * 8;
        float acc[4][8];
#pragma unroll
        for (int i = 0; i < 4; ++i)
#pragma unroll
            for (int j = 0; j < 8; ++j) acc[i][j] = 0.f;
#pragma unroll 4
        for (int j = 0; j < 128; ++j) {
            float aa[4], vv[8];
#pragma unroll
            for (int i = 0; i < 4; ++i) aa[i] = sc[(i0 + i) * 129 + j];
#pragma unroll
            for (int t = 0; t < 8; ++t) vv[t] = qs[j * 65 + d0 + t];
#pragma unroll
            for (int i = 0; i < 4; ++i)
#pragma unroll
                for (int t = 0; t < 8; ++t) acc[i][t] += aa[i] * vv[t];
        }
#pragma unroll
        for (int i = 0; i < 4; ++i)
#pragma unroll
            for (int t = 0; t < 8; ++t)
                qkv[base + (long long)(i0 + i) * 1920 + d0 + t] = acc[i][t];
    }
}

// ---------------------------------------------------------------------------
// LayerNorm 640: in stride 1920 (AO in qkv k-slice), out bf16 planes stride 640.
// ---------------------------------------------------------------------------
__global__ __launch_bounds__(256)
void ln640_split_kernel(const float* __restrict__ in, unsigned short* __restrict__ oh,
                        unsigned short* __restrict__ ol,
                        const float* __restrict__ g, const float* __restrict__ bb) {
    const int wave = threadIdx.x >> 6, lane = threadIdx.x & 63;
    const long long row = (long long)blockIdx.x * 4 + wave;
    const float* x = in + row * 1920;
    float v[10]; float s = 0.f;
#pragma unroll
    for (int i = 0; i < 10; ++i) { v[i] = x[lane + i * 64]; s += v[i]; }
#pragma unroll
    for (int o = 32; o; o >>= 1) s += __shfl_xor(s, o);
    const float mean = s * (1.f / 640.f);
    float vs = 0.f;
#pragma unroll
    for (int i = 0; i < 10; ++i) { const float d = v[i] - mean; vs += d * d; }
#pragma unroll
    for (int o = 32; o; o >>= 1) vs += __shfl_xor(vs, o);
    const float rstd = 1.f / sqrtf(vs * (1.f / 640.f) + 1e-5f);
#pragma unroll
    for (int i = 0; i < 10; ++i) {
        const int c = lane + i * 64;
        const float y = (v[i] - mean) * rstd * g[c] + bb[c];
        unsigned short h, l; split2(y, h, l);
        oh[row * 640 + c] = h; ol[row * 640 + c] = l;
    }
}

// ---------------------------------------------------------------------------
// X2 = LN( relu(C2 + b2) + X1 ), X1 reconstructed from planes; out planes.
// ---------------------------------------------------------------------------
__global__ __launch_bounds__(256)
void ln2048_split_kernel(const float* __restrict__ c2, const float* __restrict__ b2,
                         const unsigned short* __restrict__ x1h,
                         const unsigned short* __restrict__ x1l,
                         const float* __restrict__ g, const float* __restrict__ bb,
                         unsigned short* __restrict__ oh, unsigned short* __restrict__ ol) {
    const int wave = threadIdx.x >> 6, lane = threadIdx.x & 63;
    const long long row = (long long)blockIdx.x * 4 + wave;
    float v[32]; float s = 0.f;
#pragma unroll
    for (int i = 0; i < 32; ++i) {
        const int c = lane + i * 64;
        const long long ix = row * 2048 + c;
        const float x1v = bf2f(x1h[ix]) + bf2f(x1l[ix]);
        const float t = fmaxf(c2[ix] + b2[c], 0.f) + x1v;
        v[i] = t; s += t;
    }
#pragma unroll
    for (int o = 32; o; o >>= 1) s += __shfl_xor(s, o);
    const float mean = s * (1.f / 2048.f);
    float vs = 0.f;
#pragma unroll
    for (int i = 0; i < 32; ++i) { const float d = v[i] - mean; vs += d * d; }
#pragma unroll
    for (int o = 32; o; o >>= 1) vs += __shfl_xor(vs, o);
    const float rstd = 1.f / sqrtf(vs * (1.f / 2048.f) + 1e-5f);
#pragma unroll
    for (int i = 0; i < 32; ++i) {
        const int c = lane + i * 64;
        const float y = (v[i] - mean) * rstd * g[c] + bb[c];
        unsigned short h, l; split2(y, h, l);
        oh[row * 2048 + c] = h; ol[row * 2048 + c] = l;
    }
}

// ---------------------------------------------------------------------------
// Head: fc5 -> concat(last_action) -> fc6 -> exact top-64 rank mask -> softmax.
// ---------------------------------------------------------------------------
__global__ __launch_bounds__(256)
void head_kernel(const float* x4, const float* la,
                 const float* w5, const float* b5,
                 const float* w6, const float* b6, float* out) {
    __shared__ float xs[512];
    __shared__ float ys[258];
    __shared__ float scs[132];
    __shared__ int   win[132];
    __shared__ float red[2];
    const int b = blockIdx.x, tid = threadIdx.x;
    const int wave = tid >> 6, lane = tid & 63;

    xs[tid]       = x4[b * 512 + tid];
    xs[tid + 256] = x4[b * 512 + tid + 256];
    if (tid < 129) ys[129 + tid] = la[b * 129 + tid];
    __syncthreads();

    for (int n = wave; n < 129; n += 4) {
        float acc = 0.f;
        for (int k = lane; k < 512; k += 64) acc += w5[n * 512 + k] * xs[k];
#pragma unroll
        for (int o = 32; o; o >>= 1) acc += __shfl_xor(acc, o);
        if (lane == 0) ys[n] = acc + b5[n];
    }
    __syncthreads();

    for (int n = wave; n < 129; n += 4) {
        float acc = 0.f;
        for (int k = lane; k < 258; k += 64) acc += w6[n * 258 + k] * ys[k];
#pragma unroll
        for (int o = 32; o; o >>= 1) acc += __shfl_xor(acc, o);
        if (lane == 0) scs[n] = acc + b6[n];
    }
    __syncthreads();

    if (tid < 129) {
        const float x = scs[tid];
        int cnt = 0;
        for (int j = 0; j < 129; ++j) {
            const float sj = scs[j];
            cnt += (sj > x) || (sj == x && j < tid);
        }
        win[tid] = (cnt < 64) ? 1 : 0;
    }
    __syncthreads();

    if (tid < 64) {
        float m = -3.402823466e38f;
        for (int j = tid; j < 129; j += 64) if (win[j]) m = fmaxf(m, scs[j]);
#pragma unroll
        for (int o = 32; o; o >>= 1) m = fmaxf(m, __shfl_xor(m, o));
        if (tid == 0) red[0] = m;
    }
    __syncthreads();
    if (tid < 129) scs[tid] = win[tid] ? expf(scs[tid] - red[0]) : 0.f;
    __syncthreads();
    if (tid < 64) {
        float s = 0.f;
        for (int j = tid; j < 129; j += 64) s += scs[j];
#pragma unroll
        for (int o = 32; o; o >>= 1) s += __shfl_xor(s, o);
        if (tid == 0) red[1] = s;
    }
    __syncthreads();
    if (tid < 129) out[b * 129 + tid] = scs[tid] / red[1];
}

// ---------------------------------------------------------------------------
extern "C" void kernel_launch(void* const* d_in, const int* in_sizes, int n_in,
                              void* d_out, int out_size, void* d_ws, size_t ws_size,
                              hipStream_t stream) {
    (void)in_sizes; (void)n_in; (void)out_size; (void)ws_size;
    const float* hist  = (const float*)d_in[0];
    const float* la    = (const float*)d_in[1];
    const float* emb_w = (const float*)d_in[2];
    const float* emb_b = (const float*)d_in[3];
    const float* inp_w = (const float*)d_in[4];
    const float* inp_b = (const float*)d_in[5];
    const float* out_w = (const float*)d_in[6];
    const float* out_b = (const float*)d_in[7];
    const float* ln_g  = (const float*)d_in[8];
    const float* ln_b  = (const float*)d_in[9];
    const float* w1    = (const float*)d_in[10];
    const float* b1    = (const float*)d_in[11];
    const float* w2    = (const float*)d_in[12];
    const float* b2    = (const float*)d_in[13];
    const float* l1g   = (const float*)d_in[14];
    const float* l1b   = (const float*)d_in[15];
    const float* w3    = (const float*)d_in[16];
    const float* b3    = (const float*)d_in[17];
    const float* w4    = (const float*)d_in[18];
    const float* b4    = (const float*)d_in[19];
    const float* w5    = (const float*)d_in[20];
    const float* b5    = (const float*)d_in[21];
    const float* w6    = (const float*)d_in[22];
    const float* b6    = (const float*)d_in[23];

    char* ws = (char*)d_ws;
    float* qkv = (float*)(ws + WS_QKV);
    float* c1  = (float*)(ws + WS_C1);
    float* c2  = (float*)(ws + WS_C2);
    float* c3  = (float*)(ws + WS_C3);
    float* c4  = (float*)(ws + WS_C4);
    float* x4f = (float*)(ws + WS_X4F);
    typedef unsigned short u16;
    u16* hhi  = (u16*)(ws + WS_HHI);  u16* hlo  = (u16*)(ws + WS_HLO);
    u16* xhi  = (u16*)(ws + WS_XHI);  u16* xlo  = (u16*)(ws + WS_XLO);
    u16* w2hi = (u16*)(ws + WS_W2HI); u16* w2lo = (u16*)(ws + WS_W2LO);
    u16* w3hi = (u16*)(ws + WS_W3HI); u16* w3lo = (u16*)(ws + WS_W3LO);
    u16* w4hi = (u16*)(ws + WS_W4HI); u16* w4lo = (u16*)(ws + WS_W4LO);
    u16* x1hi = (u16*)(ws + WS_X1HI); u16* x1lo = (u16*)(ws + WS_X1LO);
    u16* x2hi = (u16*)(ws + WS_X2HI); u16* x2lo = (u16*)(ws + WS_X2LO);
    u16* x3hi = (u16*)(ws + WS_X3HI); u16* x3lo = (u16*)(ws + WS_X3LO);

    hipMemsetAsync(ws + WS_C1, 0, (size_t)WS_ZERO_LEN, stream);

    // 1) h = hist @ emb_w^T + emb_b   -> h planes only (both operands OTF)
    {
        MGemmP p{}; p.Af32 = hist; p.Bf32 = emb_w;
        p.Chi = hhi; p.Clo = hlo; p.bias = emb_b;
        p.lda = 640; p.ldb = 640; p.ldc = 640;
        p.kChunk = 640; p.aAlign4 = 1; p.bAlign4 = 1;
        gemm_mfma<false, true, true><<<dim3(5, 512, 1), 256, 0, stream>>>(p);
    }
    // 2) qkv = h @ inp_w^T + inp_b    (A planes, B OTF) -> qkv f32
    {
        MGemmP p{}; p.Ahi = hhi; p.Alo = hlo; p.Bf32 = inp_w;
        p.C = qkv; p.bias = inp_b;
        p.lda = 640; p.ldb = 640; p.ldc = 1920;
        p.kChunk = 640; p.bAlign4 = 1;
        gemm_mfma<false, false, true><<<dim3(15, 512, 1), 256, 0, stream>>>(p);
    }
    // 3) attention (ctx written over q slice, f32 in-place)
    attn_kernel<<<dim3(BB * NH), 256, 0, stream>>>(qkv);
    // 4) AO = ctx @ out_w^T + out_b + (hhi+hlo)  -> qkv k-slice (A,B OTF)
    {
        MGemmP p{}; p.Af32 = qkv; p.Bf32 = out_w;
        p.C = qkv + 640; p.bias = out_b;
        p.Rhi = hhi; p.Rlo = hlo; p.ldr = 640;
        p.lda = 1920; p.ldb = 640; p.ldc = 1920;
        p.kChunk = 640; p.aAlign4 = 1; p.bAlign4 = 1;
        gemm_mfma<false, true, true><<<dim3(5, 512, 1), 256, 0, stream>>>(p);
    }
    // 5) X = LN(AO) -> x planes (overwrites h planes; h dead after step 4)
    ln640_split_kernel<<<dim3(16384), 256, 0, stream>>>(qkv + 640, xhi, xlo, ln_g, ln_b);
    // 5b) split w2/w3/w4 into dead qkv region
    split_kernel<<<dim3(2048), 256, 0, stream>>>(w2, w2hi, w2lo, 1048576LL);
    split_kernel<<<dim3(2048), 256, 0, stream>>>(w3, w3hi, w3lo, 524288LL);
    split_kernel<<<dim3(512),  256, 0, stream>>>(w4, w4hi, w4lo, 131072LL);
    // 6) fc1 main: X[512,81920] @ w1[:, :81920]^T  (A planes, B=w1 f32 OTF,
    //    ldb=82049 odd -> scalar loads; split-K 16, atomic)
    {
        MGemmP p{}; p.Ahi = xhi; p.Alo = xlo; p.Bf32 = w1;
        p.C = c1;
        p.lda = 81920; p.ldb = 82049; p.ldc = 2048;
        p.kChunk = 5120; p.bAlign4 = 0;
        gemm_mfma<true, false, true><<<dim3(16, 4, 16), 256, 0, stream>>>(p);
    }
    // 6b) fc1 tail: last_action @ w1[:, 81920:]^T (fp32, atomic)
    {
        GemmP p{la, w1, c1, nullptr, nullptr, 129, 82049, 2048, 0, 81920, 82049, 129, 81920, 0};
        gemm128<true><<<dim3(4, 16, 1), 256, 0, stream>>>(p);
    }
    bias_act_split_kernel<<<dim3(4096), 256, 0, stream>>>(c1, b1, x1hi, x1lo, 2047);
    // 7) fc2 (planes/planes, split-K 4, atomic); X2 = LN(relu(c2+b2)+x1)
    {
        MGemmP p{}; p.Ahi = x1hi; p.Alo = x1lo; p.Bhi = w2hi; p.Blo = w2lo;
        p.C = c2;
        p.lda = 2048; p.ldb = 2048; p.ldc = 2048;
        p.kChunk = 512;
        gemm_mfma<true, false, false><<<dim3(16, 4, 4), 256, 0, stream>>>(p);
    }
    ln2048_split_kernel<<<dim3(128), 256, 0, stream>>>(c2, b2, x1hi, x1lo, l1g, l1b, x2hi, x2lo);
    // 8) fc3 (split-K 8)
    {
        MGemmP p{}; p.Ahi = x2hi; p.Alo = x2lo; p.Bhi = w3hi; p.Blo = w3lo;
        p.C = c3;
        p.lda = 2048; p.ldb = 2048; p.ldc = 1024;
        p.kChunk = 256;
        gemm_mfma<true, false, false><<<dim3(8, 4, 8), 256, 0, stream>>>(p);
    }
    bias_act_split_kernel<<<dim3(2048), 256, 0, stream>>>(c3, b3, x3hi, x3lo, 1023);
    // 9) fc4 (split-K 8)
    {
        MGemmP p{}; p.Ahi = x3hi; p.Alo = x3lo; p.Bhi = w4hi; p.Blo = w4lo;
        p.C = c4;
        p.lda = 1024; p.ldb = 1024; p.ldc = 512;
        p.kChunk = 128;
        gemm_mfma<true, false, false><<<dim3(4, 4, 8), 256, 0, stream>>>(p);
    }
    bias_relu_kernel<<<dim3(1024), 256, 0, stream>>>(c4, b4, x4f, 511);
    // 10) head
    head_kernel<<<dim3(512), 256, 0, stream>>>(x4f, la, w5, b5, w6, b6, (float*)d_out);
}

// Round 3
// 3927.853 us; speedup vs baseline: 2.2916x; 1.0178x over previous
//
#include <hip/hip_runtime.h>

// ---------------------------------------------------------------------------
// PolicyNet2 forward. bf16x3 split-MFMA GEMMs. Cheap truncation-split for
// on-the-fly f32->bf16 staging; small weights pre-split into scratch planes.
// B=512 S=128 E=640 A=129 H=2048 NHEADS=10 HD=64 K_WIN=64
// Workspace footprint: exactly 694,157,312 bytes (proven max).
// ---------------------------------------------------------------------------

#define BB   512
#define SS   128
#define EE   640
#define AA   129
#define HH   2048
#define NH   10
#define HD   64

// ---------------- workspace layout (bytes) ----------------
#define WS_QKV      0LL            // [65536,1920] f32 qkv; ctx in q-slice; AO in k-slice
#define WS_W2HI     0LL            // post-LN640: qkv dead -> w2/w3/w4 planes
#define WS_W2LO     8388608LL
#define WS_W3HI     16777216LL
#define WS_W3LO     20971520LL
#define WS_W4HI     25165824LL
#define WS_W4LO     26214400LL
#define WS_HHI      503316480LL    // [65536,640] u16 h hi ; later x hi
#define WS_HLO      587202560LL    // [65536,640] u16 h lo ; later x lo
#define WS_XHI      503316480LL
#define WS_XLO      587202560LL
// C region (671088640 .. 682622976): first small-weight planes, then C1..C4
#define WS_EMBHI    671088640LL    // [640,640]  u16  (pre-fc1 phase only)
#define WS_EMBLO    671907840LL
#define WS_INPHI    672727040LL    // [1920,640] u16
#define WS_INPLO    675184640LL
#define WS_OUTHI    677642240LL    // [640,640]  u16
#define WS_OUTLO    678461440LL
#define WS_C1       671088640LL    // [512,2048] f32 (after memset, post-LN640)
#define WS_C2       675282944LL    // [512,2048]
#define WS_C3       679477248LL    // [512,1024]
#define WS_C4       681574400LL    // [512,512]
#define WS_X1HI     682622976LL    // [512,2048] u16
#define WS_X1LO     684720128LL
#define WS_X2HI     686817280LL
#define WS_X2LO     688914432LL
#define WS_X3HI     691011584LL    // [512,1024] u16
#define WS_X3LO     692060160LL
#define WS_X4F      693108736LL    // [512,512] f32  (ends at 694,157,312)
#define WS_ZERO_LEN 11534336LL     // C1..C4 contiguous

typedef __bf16 bf16x8 __attribute__((ext_vector_type(8)));
typedef float  f32x4  __attribute__((ext_vector_type(4)));
typedef unsigned short us8 __attribute__((ext_vector_type(8)));
typedef unsigned short us4 __attribute__((ext_vector_type(4)));

// ---------------- fp32 -> bf16 hi/lo splits ----------------
// RNE split (plane-producing passes; memory-bound, precision free)
__device__ __forceinline__ unsigned int bf16_rne(float x) {
    unsigned int u = __float_as_uint(x);
    return (u + 0x7fffu + ((u >> 16) & 1u)) >> 16;
}
__device__ __forceinline__ void split2(float x, unsigned short& h, unsigned short& l) {
    const unsigned int hb = bf16_rne(x);
    const float hf = __uint_as_float(hb << 16);
    const unsigned int lb = bf16_rne(x - hf);
    h = (unsigned short)hb; l = (unsigned short)lb;
}
// cheap truncation split (OTF staging path; ~4 VALU/elem, err < 2^-16 rel)
__device__ __forceinline__ void split2fast(float x, unsigned short& h, unsigned short& l) {
    const unsigned int u  = __float_as_uint(x);
    const unsigned int hb = u & 0xffff0000u;
    const float lf = x - __uint_as_float(hb);
    h = (unsigned short)(u >> 16);
    l = (unsigned short)(__float_as_uint(lf) >> 16);
}
__device__ __forceinline__ float bf2f(unsigned short v) {
    return __uint_as_float((unsigned int)v << 16);
}

// ---------------- async global->LDS, 16B/lane ----------------
__device__ __forceinline__ void gload16(const unsigned short* g, unsigned short* l) {
    __builtin_amdgcn_global_load_lds(
        (__attribute__((address_space(1))) unsigned int*)g,
        (__attribute__((address_space(3))) unsigned int*)l, 16, 0, 0);
}

// stage 8 f32 -> 8 bf16-hi + 8 bf16-lo into LDS (16B each), cheap split
__device__ __forceinline__ void stage_otf(const float* src, int align4,
                                          unsigned short* dhi, unsigned short* dlo) {
    float f[8];
    if (align4) {
        const float4 v0 = *reinterpret_cast<const float4*>(src);
        const float4 v1 = *reinterpret_cast<const float4*>(src + 4);
        f[0] = v0.x; f[1] = v0.y; f[2] = v0.z; f[3] = v0.w;
        f[4] = v1.x; f[5] = v1.y; f[6] = v1.z; f[7] = v1.w;
    } else {
#pragma unroll
        for (int j = 0; j < 8; ++j) f[j] = src[j];
    }
    us8 h, l;
#pragma unroll
    for (int j = 0; j < 8; ++j) {
        unsigned short hh, ll; split2fast(f[j], hh, ll);
        h[j] = hh; l[j] = ll;
    }
    *reinterpret_cast<us8*>(dhi) = h;
    *reinterpret_cast<us8*>(dlo) = l;
}

// ---------------------------------------------------------------------------
// MFMA bf16x3 GEMM: C[m,n] (+)= sum_k A[m,k]*B[n,k]
// Plane operands: global_load_lds width-16. f32 operands: reg-stage + cheap
// split. 128x128 tile, BK=32, 256 thr (4 waves, 64x64 each = 4x4 16x16x32).
// LDS 16B-chunk swizzle: chunk(row r, slot s) at r*4 + (s ^ ((r>>1)&3));
// both staging paths write the identical layout (inverse swizzle on source).
// ---------------------------------------------------------------------------
struct MGemmP {
    const unsigned short *Ahi, *Alo, *Bhi, *Blo;   // plane path
    const float *Af32, *Bf32;                      // on-the-fly path
    float* C;
    const float* bias; const float* resid;
    const unsigned short *Rhi, *Rlo;               // resid from planes (hi+lo)
    unsigned short *Chi, *Clo;                     // optional plane outputs
    long long lda, ldb, ldc, ldr;                  // element strides
    int kChunk; int act; int aAlign4, bAlign4;
};

template <bool ATOMIC, bool AOTF, bool BOTF>
__global__ __launch_bounds__(256, 2)
void gemm_mfma(MGemmP p) {
    __shared__ __align__(16) unsigned short sAhi[4096];
    __shared__ __align__(16) unsigned short sAlo[4096];
    __shared__ __align__(16) unsigned short sBhi[4096];
    __shared__ __align__(16) unsigned short sBlo[4096];
    const int tid = threadIdx.x;
    const int lane = tid & 63, wave = tid >> 6;
    const int n0 = blockIdx.x * 128, m0 = blockIdx.y * 128;
    const long long kS = (long long)blockIdx.z * p.kChunk;
    const long long kE = kS + p.kChunk;
    const int wr = (wave >> 1) * 64, wc = (wave & 1) * 64;

    // fragment LDS offsets (swizzled), conflict-free ds_read_b128
    int aoff[4], boff[4];
#pragma unroll
    for (int i = 0; i < 4; ++i) {
        const int ks = lane >> 4;
        const int ar = wr + i * 16 + (lane & 15);
        aoff[i] = (ar * 4 + (ks ^ ((ar >> 1) & 3))) * 8;
        const int br = wc + i * 16 + (lane & 15);
        boff[i] = (br * 4 + (ks ^ ((br >> 1) & 3))) * 8;
    }

    // staging coords: 2 rounds x 256 chunks of 16B; source slot inverse-swizzled
    long long gA[2], gB[2];
    int ldsU[2], ldsP[2];
#pragma unroll
    for (int c = 0; c < 2; ++c) {
        const int ch = c * 256 + tid;
        const int r  = ch >> 2;
        const int s  = (ch & 3) ^ ((r >> 1) & 3);
        gA[c] = (long long)(m0 + r) * p.lda + s * 8;
        gB[c] = (long long)(n0 + r) * p.ldb + s * 8;
        ldsU[c] = (c * 256 + wave * 64) * 8;   // wave-uniform base for gload_lds
        ldsP[c] = ch * 8;                      // per-lane for ds_write path
    }

    f32x4 acc[4][4];
    const f32x4 zero = {0.f, 0.f, 0.f, 0.f};
#pragma unroll
    for (int i = 0; i < 4; ++i)
#pragma unroll
        for (int j = 0; j < 4; ++j) acc[i][j] = zero;

    for (long long kt = kS; kt < kE; kt += 32) {
#pragma unroll
        for (int c = 0; c < 2; ++c) {
            if (AOTF) {
                stage_otf(p.Af32 + gA[c] + kt, p.aAlign4, &sAhi[ldsP[c]], &sAlo[ldsP[c]]);
            } else {
                gload16(p.Ahi + gA[c] + kt, &sAhi[ldsU[c]]);
                gload16(p.Alo + gA[c] + kt, &sAlo[ldsU[c]]);
            }
            if (BOTF) {
                stage_otf(p.Bf32 + gB[c] + kt, p.bAlign4, &sBhi[ldsP[c]], &sBlo[ldsP[c]]);
            } else {
                gload16(p.Bhi + gB[c] + kt, &sBhi[ldsU[c]]);
                gload16(p.Blo + gB[c] + kt, &sBlo[ldsU[c]]);
            }
        }
        __syncthreads();
        bf16x8 ah[4], al[4], bh[4], bl[4];
#pragma unroll
        for (int i = 0; i < 4; ++i) {
            ah[i] = *(const bf16x8*)&sAhi[aoff[i]];
            al[i] = *(const bf16x8*)&sAlo[aoff[i]];
            bh[i] = *(const bf16x8*)&sBhi[boff[i]];
            bl[i] = *(const bf16x8*)&sBlo[boff[i]];
        }
#pragma unroll
        for (int mi = 0; mi < 4; ++mi)
#pragma unroll
            for (int ni = 0; ni < 4; ++ni) {
                acc[mi][ni] = __builtin_amdgcn_mfma_f32_16x16x32_bf16(ah[mi], bh[ni], acc[mi][ni], 0, 0, 0);
                acc[mi][ni] = __builtin_amdgcn_mfma_f32_16x16x32_bf16(ah[mi], bl[ni], acc[mi][ni], 0, 0, 0);
                acc[mi][ni] = __builtin_amdgcn_mfma_f32_16x16x32_bf16(al[mi], bh[ni], acc[mi][ni], 0, 0, 0);
            }
        __syncthreads();
    }

    // epilogue: C/D frag layout col=lane&15, row=(lane>>4)*4+reg  [m89/m91]
    const int rb = (lane >> 4) * 4, ci = lane & 15;
#pragma unroll
    for (int mi = 0; mi < 4; ++mi)
#pragma unroll
        for (int r = 0; r < 4; ++r) {
            const long long row = (long long)(m0 + wr + mi * 16 + rb + r);
#pragma unroll
            for (int ni = 0; ni < 4; ++ni) {
                const int col = n0 + wc + ni * 16 + ci;
                float v = acc[mi][ni][r];
                if (ATOMIC) {
                    unsafeAtomicAdd(&p.C[row * p.ldc + col], v);
                } else {
                    if (p.bias)  v += p.bias[col];
                    if (p.resid) v += p.resid[row * p.ldr + col];
                    if (p.Rhi) {
                        const long long ri = row * p.ldr + col;
                        v += bf2f(p.Rhi[ri]) + bf2f(p.Rlo[ri]);
                    }
                    if (p.act)   v = fmaxf(v, 0.f);
                    if (p.C)     p.C[row * p.ldc + col] = v;
                    if (p.Chi) {
                        unsigned short h, l; split2(v, h, l);
                        p.Chi[row * p.ldc + col] = h;
                        p.Clo[row * p.ldc + col] = l;
                    }
                }
            }
        }
}

// ---------------------------------------------------------------------------
// fp32 fallback GEMM (only fc1's 129-wide last_action tail). Proven.
// ---------------------------------------------------------------------------
struct GemmP {
    const float* A; const float* B; float* C;
    const float* bias; const float* resid;
    int lda, ldb, ldc, ldr;
    int kStart, kEnd, kChunk, kOffA;
    int act;
};

template <bool ATOMIC>
__global__ __launch_bounds__(256)
void gemm128(GemmP p) {
    __shared__ float As[16 * 128];
    __shared__ float Bs[16 * 128];
    const int tid = threadIdx.x;
    const int m0 = blockIdx.x * 128;
    const int n0 = blockIdx.y * 128;
    int kS = p.kStart + (int)blockIdx.z * p.kChunk;
    int kE = kS + p.kChunk; if (kE > p.kEnd) kE = p.kEnd;
    const int tx = tid & 15, ty = tid >> 4;

    float acc[8][8];
#pragma unroll
    for (int i = 0; i < 8; ++i)
#pragma unroll
        for (int j = 0; j < 8; ++j) acc[i][j] = 0.f;

    const bool a4 = ((p.lda & 3) == 0);
    const bool b4 = ((p.ldb & 3) == 0);

    for (int kt = kS; kt < kE; kt += 16) {
#pragma unroll
        for (int it = 0; it < 2; ++it) {
            const int slot = tid + it * 256;
            const int row = slot >> 2;
            const int kq  = (slot & 3) << 2;
            const int k   = kt + kq;
            {
                const float* ap = p.A + (long long)(m0 + row) * p.lda + (k - p.kOffA);
                float4 v;
                if (a4 && (k + 4 <= kE)) {
                    v = *reinterpret_cast<const float4*>(ap);
                } else {
                    v.x = (k + 0 < kE) ? ap[0] : 0.f;
                    v.y = (k + 1 < kE) ? ap[1] : 0.f;
                    v.z = (k + 2 < kE) ? ap[2] : 0.f;
                    v.w = (k + 3 < kE) ? ap[3] : 0.f;
                }
                As[(kq + 0) * 128 + row] = v.x;
                As[(kq + 1) * 128 + row] = v.y;
                As[(kq + 2) * 128 + row] = v.z;
                As[(kq + 3) * 128 + row] = v.w;
            }
            {
                const float* bp = p.B + (long long)(n0 + row) * p.ldb + k;
                float4 v;
                if (b4 && (k + 4 <= kE)) {
                    v = *reinterpret_cast<const float4*>(bp);
                } else {
                    v.x = (k + 0 < kE) ? bp[0] : 0.f;
                    v.y = (k + 1 < kE) ? bp[1] : 0.f;
                    v.z = (k + 2 < kE) ? bp[2] : 0.f;
                    v.w = (k + 3 < kE) ? bp[3] : 0.f;
                }
                Bs[(kq + 0) * 128 + row] = v.x;
                Bs[(kq + 1) * 128 + row] = v.y;
                Bs[(kq + 2) * 128 + row] = v.z;
                Bs[(kq + 3) * 128 + row] = v.w;
            }
        }
        __syncthreads();
#pragma unroll
        for (int kk = 0; kk < 16; ++kk) {
            float a[8], b[8];
            *reinterpret_cast<float4*>(&a[0]) = *reinterpret_cast<const float4*>(&As[kk * 128 + ty * 8]);
            *reinterpret_cast<float4*>(&a[4]) = *reinterpret_cast<const float4*>(&As[kk * 128 + ty * 8 + 4]);
            *reinterpret_cast<float4*>(&b[0]) = *reinterpret_cast<const float4*>(&Bs[kk * 128 + tx * 8]);
            *reinterpret_cast<float4*>(&b[4]) = *reinterpret_cast<const float4*>(&Bs[kk * 128 + tx * 8 + 4]);
#pragma unroll
            for (int i = 0; i < 8; ++i)
#pragma unroll
                for (int j = 0; j < 8; ++j) acc[i][j] += a[i] * b[j];
        }
        __syncthreads();
    }

#pragma unroll
    for (int i = 0; i < 8; ++i) {
        const int row = m0 + ty * 8 + i;
        const long long cb = (long long)row * p.ldc + n0 + tx * 8;
        if (ATOMIC) {
#pragma unroll
            for (int j = 0; j < 8; ++j) unsafeAtomicAdd(&p.C[cb + j], acc[i][j]);
        } else {
            const long long rb = (long long)row * p.ldr + n0 + tx * 8;
#pragma unroll
            for (int j = 0; j < 8; ++j) {
                float v = acc[i][j];
                if (p.bias)  v += p.bias[n0 + tx * 8 + j];
                if (p.resid) v += p.resid[rb + j];
                if (p.act)   v = fmaxf(v, 0.f);
                p.C[cb + j] = v;
            }
        }
    }
}

// ---------------------------------------------------------------------------
// split: fp32 -> bf16 hi/lo planes (weights; RNE)
// ---------------------------------------------------------------------------
__global__ __launch_bounds__(256)
void split_kernel(const float* __restrict__ in, unsigned short* __restrict__ hi,
                  unsigned short* __restrict__ lo, long long n4) {
    const long long stride = (long long)gridDim.x * 256;
    for (long long i = (long long)blockIdx.x * 256 + threadIdx.x; i < n4; i += stride) {
        const float4 v = reinterpret_cast<const float4*>(in)[i];
        unsigned short h0, h1, h2, h3, l0, l1, l2, l3;
        split2(v.x, h0, l0); split2(v.y, h1, l1);
        split2(v.z, h2, l2); split2(v.w, h3, l3);
        us4 hv = {h0, h1, h2, h3};
        us4 lv = {l0, l1, l2, l3};
        reinterpret_cast<us4*>(hi)[i] = hv;
        reinterpret_cast<us4*>(lo)[i] = lv;
    }
}

// out planes = split(relu(c + bias))
__global__ __launch_bounds__(256)
void bias_act_split_kernel(const float* __restrict__ c, const float* __restrict__ bias,
                           unsigned short* __restrict__ hi,
                           unsigned short* __restrict__ lo, int mask) {
    const int idx = blockIdx.x * 256 + threadIdx.x;
    const float v = fmaxf(c[idx] + bias[idx & mask], 0.f);
    unsigned short h, l; split2(v, h, l);
    hi[idx] = h; lo[idx] = l;
}

__global__ __launch_bounds__(256)
void bias_relu_kernel(const float* c, const float* bias, float* out, int mask) {
    const int idx = blockIdx.x * 256 + threadIdx.x;
    out[idx] = fmaxf(c[idx] + bias[idx & mask], 0.f);
}

// ---------------------------------------------------------------------------
// Attention: one workgroup per (b, head). In-place: ctx -> q slice. (proven)
// ---------------------------------------------------------------------------
__global__ __launch_bounds__(256)
void attn_kernel(float* qkv) {
    __shared__ float qs[128 * 65];
    __shared__ float ks[128 * 65];
    __shared__ float sc[128 * 129];
    const int tid = threadIdx.x;
    const int b = blockIdx.x / NH, h = blockIdx.x % NH;
    const long long base = (long long)b * SS * (3 * EE) + h * HD;

    for (int idx = tid; idx < 128 * 64; idx += 256) {
        const int s = idx >> 6, d = idx & 63;
        qs[s * 65 + d] = qkv[base + (long long)s * 1920 + d] * 0.125f;
        ks[s * 65 + d] = qkv[base + 640 + (long long)s * 1920 + d];
    }
    __syncthreads();

    {
        const int tx = tid & 15, ty = tid >> 4;
        const int i0 = ty * 8, j0 = tx * 8;
        float acc[8][8];
#pragma unroll
        for (int i = 0; i < 8; ++i)
#pragma unroll
            for (int j = 0; j < 8; ++j) acc[i][j] = 0.f;
#pragma unroll 4
        for (int d = 0; d < 64; ++d) {
            float qa[8], kb[8];
#pragma unroll
            for (int i = 0; i < 8; ++i) qa[i] = qs[(i0 + i) * 65 + d];
#pragma unroll
            for (int j = 0; j < 8; ++j) kb[j] = ks[(j0 + j) * 65 + d];
#pragma unroll
            for (int i = 0; i < 8; ++i)
#pragma unroll
                for (int j = 0; j < 8; ++j) acc[i][j] += qa[i] * kb[j];
        }
#pragma unroll
        for (int i = 0; i < 8; ++i)
#pragma unroll
            for (int j = 0; j < 8; ++j) sc[(i0 + i) * 129 + (j0 + j)] = acc[i][j];
    }
    __syncthreads();

    if (tid < 128) {
        const int r = tid;
        float m = -3.402823466e38f;
        for (int j = 0; j < 128; ++j) m = fmaxf(m, sc[r * 129 + j]);
        float sum = 0.f;
        for (int j = 0; j < 128; ++j) {
            const float e = expf(sc[r * 129 + j] - m);
            sc[r * 129 + j] = e; sum += e;
        }
        const float inv = 1.f / sum;
        for (int j = 0; j < 128; ++j) sc[r * 129 + j] *= inv;
    }
    __syncthreads();

    for (int idx = tid; idx < 128 * 64; idx += 256) {
        const int s = idx >> 6, d = idx & 63;
        qs[s * 65 + d] = qkv[base + 1280 + (long long)s * 1920 + d];
    }
    __syncthreads();

    {
        const int cx = tid & 7, cy = tid >> 3;
        const int i0 = cy * 4, d0 = cx * 8;
        float acc[4][8];
#pragma unroll
        for (int i = 0; i < 4; ++i)
#pragma unroll
            for (int j = 0; j < 8; ++j) acc[i][j] = 0.f;
#pragma unroll 4
        for (int j = 0; j < 128; ++j) {
            float aa[4], vv[8];
#pragma unroll
            for (int i = 0; i < 4; ++i) aa[i] = sc[(i0 + i) * 129 + j];
#pragma unroll
            for (int t = 0; t < 8; ++t) vv[t] = qs[j * 65 + d0 + t];
#pragma unroll
            for (int i = 0; i < 4; ++i)
#pragma unroll
                for (int t = 0; t < 8; ++t) acc[i][t] += aa[i] * vv[t];
        }
#pragma unroll
        for (int i = 0; i < 4; ++i)
#pragma unroll
            for (int t = 0; t < 8; ++t)
                qkv[base + (long long)(i0 + i) * 1920 + d0 + t] = acc[i][t];
    }
}

// ---------------------------------------------------------------------------
// LayerNorm 640: in stride 1920 (AO in qkv k-slice), out bf16 planes stride 640.
// ---------------------------------------------------------------------------
__global__ __launch_bounds__(256)
void ln640_split_kernel(const float* __restrict__ in, unsigned short* __restrict__ oh,
                        unsigned short* __restrict__ ol,
                        const float* __restrict__ g, const float* __restrict__ bb) {
    const int wave = threadIdx.x >> 6, lane = threadIdx.x & 63;
    const long long row = (long long)blockIdx.x * 4 + wave;
    const float* x = in + row * 1920;
    float v[10]; float s = 0.f;
#pragma unroll
    for (int i = 0; i < 10; ++i) { v[i] = x[lane + i * 64]; s += v[i]; }
#pragma unroll
    for (int o = 32; o; o >>= 1) s += __shfl_xor(s, o);
    const float mean = s * (1.f / 640.f);
    float vs = 0.f;
#pragma unroll
    for (int i = 0; i < 10; ++i) { const float d = v[i] - mean; vs += d * d; }
#pragma unroll
    for (int o = 32; o; o >>= 1) vs += __shfl_xor(vs, o);
    const float rstd = 1.f / sqrtf(vs * (1.f / 640.f) + 1e-5f);
#pragma unroll
    for (int i = 0; i < 10; ++i) {
        const int c = lane + i * 64;
        const float y = (v[i] - mean) * rstd * g[c] + bb[c];
        unsigned short h, l; split2(y, h, l);
        oh[row * 640 + c] = h; ol[row * 640 + c] = l;
    }
}

// ---------------------------------------------------------------------------
// X2 = LN( relu(C2 + b2) + X1 ), X1 reconstructed from planes; out planes.
// ---------------------------------------------------------------------------
__global__ __launch_bounds__(256)
void ln2048_split_kernel(const float* __restrict__ c2, const float* __restrict__ b2,
                         const unsigned short* __restrict__ x1h,
                         const unsigned short* __restrict__ x1l,
                         const float* __restrict__ g, const float* __restrict__ bb,
                         unsigned short* __restrict__ oh, unsigned short* __restrict__ ol) {
    const int wave = threadIdx.x >> 6, lane = threadIdx.x & 63;
    const long long row = (long long)blockIdx.x * 4 + wave;
    float v[32]; float s = 0.f;
#pragma unroll
    for (int i = 0; i < 32; ++i) {
        const int c = lane + i * 64;
        const long long ix = row * 2048 + c;
        const float x1v = bf2f(x1h[ix]) + bf2f(x1l[ix]);
        const float t = fmaxf(c2[ix] + b2[c], 0.f) + x1v;
        v[i] = t; s += t;
    }
#pragma unroll
    for (int o = 32; o; o >>= 1) s += __shfl_xor(s, o);
    const float mean = s * (1.f / 2048.f);
    float vs = 0.f;
#pragma unroll
    for (int i = 0; i < 32; ++i) { const float d = v[i] - mean; vs += d * d; }
#pragma unroll
    for (int o = 32; o; o >>= 1) vs += __shfl_xor(vs, o);
    const float rstd = 1.f / sqrtf(vs * (1.f / 2048.f) + 1e-5f);
#pragma unroll
    for (int i = 0; i < 32; ++i) {
        const int c = lane + i * 64;
        const float y = (v[i] - mean) * rstd * g[c] + bb[c];
        unsigned short h, l; split2(y, h, l);
        oh[row * 2048 + c] = h; ol[row * 2048 + c] = l;
    }
}

// ---------------------------------------------------------------------------
// Head: fc5 -> concat(last_action) -> fc6 -> exact top-64 rank mask -> softmax.
// ---------------------------------------------------------------------------
__global__ __launch_bounds__(256)
void head_kernel(const float* x4, const float* la,
                 const float* w5, const float* b5,
                 const float* w6, const float* b6, float* out) {
    __shared__ float xs[512];
    __shared__ float ys[258];
    __shared__ float scs[132];
    __shared__ int   win[132];
    __shared__ float red[2];
    const int b = blockIdx.x, tid = threadIdx.x;
    const int wave = tid >> 6, lane = tid & 63;

    xs[tid]       = x4[b * 512 + tid];
    xs[tid + 256] = x4[b * 512 + tid + 256];
    if (tid < 129) ys[129 + tid] = la[b * 129 + tid];
    __syncthreads();

    for (int n = wave; n < 129; n += 4) {
        float acc = 0.f;
        for (int k = lane; k < 512; k += 64) acc += w5[n * 512 + k] * xs[k];
#pragma unroll
        for (int o = 32; o; o >>= 1) acc += __shfl_xor(acc, o);
        if (lane == 0) ys[n] = acc + b5[n];
    }
    __syncthreads();

    for (int n = wave; n < 129; n += 4) {
        float acc = 0.f;
        for (int k = lane; k < 258; k += 64) acc += w6[n * 258 + k] * ys[k];
#pragma unroll
        for (int o = 32; o; o >>= 1) acc += __shfl_xor(acc, o);
        if (lane == 0) scs[n] = acc + b6[n];
    }
    __syncthreads();

    if (tid < 129) {
        const float x = scs[tid];
        int cnt = 0;
        for (int j = 0; j < 129; ++j) {
            const float sj = scs[j];
            cnt += (sj > x) || (sj == x && j < tid);
        }
        win[tid] = (cnt < 64) ? 1 : 0;
    }
    __syncthreads();

    if (tid < 64) {
        float m = -3.402823466e38f;
        for (int j = tid; j < 129; j += 64) if (win[j]) m = fmaxf(m, scs[j]);
#pragma unroll
        for (int o = 32; o; o >>= 1) m = fmaxf(m, __shfl_xor(m, o));
        if (tid == 0) red[0] = m;
    }
    __syncthreads();
    if (tid < 129) scs[tid] = win[tid] ? expf(scs[tid] - red[0]) : 0.f;
    __syncthreads();
    if (tid < 64) {
        float s = 0.f;
        for (int j = tid; j < 129; j += 64) s += scs[j];
#pragma unroll
        for (int o = 32; o; o >>= 1) s += __shfl_xor(s, o);
        if (tid == 0) red[1] = s;
    }
    __syncthreads();
    if (tid < 129) out[b * 129 + tid] = scs[tid] / red[1];
}

// ---------------------------------------------------------------------------
extern "C" void kernel_launch(void* const* d_in, const int* in_sizes, int n_in,
                              void* d_out, int out_size, void* d_ws, size_t ws_size,
                              hipStream_t stream) {
    (void)in_sizes; (void)n_in; (void)out_size; (void)ws_size;
    const float* hist  = (const float*)d_in[0];
    const float* la    = (const float*)d_in[1];
    const float* emb_w = (const float*)d_in[2];
    const float* emb_b = (const float*)d_in[3];
    const float* inp_w = (const float*)d_in[4];
    const float* inp_b = (const float*)d_in[5];
    const float* out_w = (const float*)d_in[6];
    const float* out_b = (const float*)d_in[7];
    const float* ln_g  = (const float*)d_in[8];
    const float* ln_b  = (const float*)d_in[9];
    const float* w1    = (const float*)d_in[10];
    const float* b1    = (const float*)d_in[11];
    const float* w2    = (const float*)d_in[12];
    const float* b2    = (const float*)d_in[13];
    const float* l1g   = (const float*)d_in[14];
    const float* l1b   = (const float*)d_in[15];
    const float* w3    = (const float*)d_in[16];
    const float* b3    = (const float*)d_in[17];
    const float* w4    = (const float*)d_in[18];
    const float* b4    = (const float*)d_in[19];
    const float* w5    = (const float*)d_in[20];
    const float* b5    = (const float*)d_in[21];
    const float* w6    = (const float*)d_in[22];
    const float* b6    = (const float*)d_in[23];

    char* ws = (char*)d_ws;
    float* qkv = (float*)(ws + WS_QKV);
    float* c1  = (float*)(ws + WS_C1);
    float* c2  = (float*)(ws + WS_C2);
    float* c3  = (float*)(ws + WS_C3);
    float* c4  = (float*)(ws + WS_C4);
    float* x4f = (float*)(ws + WS_X4F);
    typedef unsigned short u16;
    u16* hhi  = (u16*)(ws + WS_HHI);  u16* hlo  = (u16*)(ws + WS_HLO);
    u16* xhi  = (u16*)(ws + WS_XHI);  u16* xlo  = (u16*)(ws + WS_XLO);
    u16* embhi= (u16*)(ws + WS_EMBHI);u16* emblo= (u16*)(ws + WS_EMBLO);
    u16* inphi= (u16*)(ws + WS_INPHI);u16* inplo= (u16*)(ws + WS_INPLO);
    u16* outhi= (u16*)(ws + WS_OUTHI);u16* outlo= (u16*)(ws + WS_OUTLO);
    u16* w2hi = (u16*)(ws + WS_W2HI); u16* w2lo = (u16*)(ws + WS_W2LO);
    u16* w3hi = (u16*)(ws + WS_W3HI); u16* w3lo = (u16*)(ws + WS_W3LO);
    u16* w4hi = (u16*)(ws + WS_W4HI); u16* w4lo = (u16*)(ws + WS_W4LO);
    u16* x1hi = (u16*)(ws + WS_X1HI); u16* x1lo = (u16*)(ws + WS_X1LO);
    u16* x2hi = (u16*)(ws + WS_X2HI); u16* x2lo = (u16*)(ws + WS_X2LO);
    u16* x3hi = (u16*)(ws + WS_X3HI); u16* x3lo = (u16*)(ws + WS_X3LO);

    // 0) pre-split small, heavily-reused weights into C scratch (dead till fc1)
    split_kernel<<<dim3(400),  256, 0, stream>>>(emb_w, embhi, emblo, 102400LL);
    split_kernel<<<dim3(1200), 256, 0, stream>>>(inp_w, inphi, inplo, 307200LL);
    split_kernel<<<dim3(400),  256, 0, stream>>>(out_w, outhi, outlo, 102400LL);

    // 1) h = hist @ emb_w^T + emb_b   -> h planes (A OTF cheap, B planes)
    {
        MGemmP p{}; p.Af32 = hist; p.Bhi = embhi; p.Blo = emblo;
        p.Chi = hhi; p.Clo = hlo; p.bias = emb_b;
        p.lda = 640; p.ldb = 640; p.ldc = 640;
        p.kChunk = 640; p.aAlign4 = 1;
        gemm_mfma<false, true, false><<<dim3(5, 512, 1), 256, 0, stream>>>(p);
    }
    // 2) qkv = h @ inp_w^T + inp_b    (A planes, B planes) -> qkv f32
    {
        MGemmP p{}; p.Ahi = hhi; p.Alo = hlo; p.Bhi = inphi; p.Blo = inplo;
        p.C = qkv; p.bias = inp_b;
        p.lda = 640; p.ldb = 640; p.ldc = 1920;
        p.kChunk = 640;
        gemm_mfma<false, false, false><<<dim3(15, 512, 1), 256, 0, stream>>>(p);
    }
    // 3) attention (ctx written over q slice, f32 in-place)
    attn_kernel<<<dim3(BB * NH), 256, 0, stream>>>(qkv);
    // 4) AO = ctx @ out_w^T + out_b + (hhi+hlo)  -> qkv k-slice (A OTF, B planes)
    {
        MGemmP p{}; p.Af32 = qkv; p.Bhi = outhi; p.Blo = outlo;
        p.C = qkv + 640; p.bias = out_b;
        p.Rhi = hhi; p.Rlo = hlo; p.ldr = 640;
        p.lda = 1920; p.ldb = 640; p.ldc = 1920;
        p.kChunk = 640; p.aAlign4 = 1;
        gemm_mfma<false, true, false><<<dim3(5, 512, 1), 256, 0, stream>>>(p);
    }
    // 5) X = LN(AO) -> x planes (overwrites h planes; h dead after step 4)
    ln640_split_kernel<<<dim3(16384), 256, 0, stream>>>(qkv + 640, xhi, xlo, ln_g, ln_b);
    // 5a) C1..C4 zero (weight planes in this region are dead now)
    hipMemsetAsync(ws + WS_C1, 0, (size_t)WS_ZERO_LEN, stream);
    // 5b) split w2/w3/w4 into dead qkv region
    split_kernel<<<dim3(2048), 256, 0, stream>>>(w2, w2hi, w2lo, 1048576LL);
    split_kernel<<<dim3(2048), 256, 0, stream>>>(w3, w3hi, w3lo, 524288LL);
    split_kernel<<<dim3(512),  256, 0, stream>>>(w4, w4hi, w4lo, 131072LL);
    // 6) fc1 main: X[512,81920] @ w1[:, :81920]^T  (A planes, B=w1 f32 OTF
    //    cheap-split; ldb=82049 odd -> scalar loads; split-K 16, atomic)
    {
        MGemmP p{}; p.Ahi = xhi; p.Alo = xlo; p.Bf32 = w1;
        p.C = c1;
        p.lda = 81920; p.ldb = 82049; p.ldc = 2048;
        p.kChunk = 5120; p.bAlign4 = 0;
        gemm_mfma<true, false, true><<<dim3(16, 4, 16), 256, 0, stream>>>(p);
    }
    // 6b) fc1 tail: last_action @ w1[:, 81920:]^T (fp32, atomic)
    {
        GemmP p{la, w1, c1, nullptr, nullptr, 129, 82049, 2048, 0, 81920, 82049, 129, 81920, 0};
        gemm128<true><<<dim3(4, 16, 1), 256, 0, stream>>>(p);
    }
    bias_act_split_kernel<<<dim3(4096), 256, 0, stream>>>(c1, b1, x1hi, x1lo, 2047);
    // 7) fc2 (planes/planes, split-K 4, atomic); X2 = LN(relu(c2+b2)+x1)
    {
        MGemmP p{}; p.Ahi = x1hi; p.Alo = x1lo; p.Bhi = w2hi; p.Blo = w2lo;
        p.C = c2;
        p.lda = 2048; p.ldb = 2048; p.ldc = 2048;
        p.kChunk = 512;
        gemm_mfma<true, false, false><<<dim3(16, 4, 4), 256, 0, stream>>>(p);
    }
    ln2048_split_kernel<<<dim3(128), 256, 0, stream>>>(c2, b2, x1hi, x1lo, l1g, l1b, x2hi, x2lo);
    // 8) fc3 (split-K 8)
    {
        MGemmP p{}; p.Ahi = x2hi; p.Alo = x2lo; p.Bhi = w3hi; p.Blo = w3lo;
        p.C = c3;
        p.lda = 2048; p.ldb = 2048; p.ldc = 1024;
        p.kChunk = 256;
        gemm_mfma<true, false, false><<<dim3(8, 4, 8), 256, 0, stream>>>(p);
    }
    bias_act_split_kernel<<<dim3(2048), 256, 0, stream>>>(c3, b3, x3hi, x3lo, 1023);
    // 9) fc4 (split-K 8)
    {
        MGemmP p{}; p.Ahi = x3hi; p.Alo = x3lo; p.Bhi = w4hi; p.Blo = w4lo;
        p.C = c4;
        p.lda = 1024; p.ldb = 1024; p.ldc = 512;
        p.kChunk = 128;
        gemm_mfma<true, false, false><<<dim3(4, 4, 8), 256, 0, stream>>>(p);
    }
    bias_relu_kernel<<<dim3(1024), 256, 0, stream>>>(c4, b4, x4f, 511);
    // 10) head
    head_kernel<<<dim3(512), 256, 0, stream>>>(x4f, la, w5, b5, w6, b6, (float*)d_out);
}